// Round 1
// 291.665 us; speedup vs baseline: 1.2725x; 1.2725x over previous
//
#include <hip/hip_runtime.h>
#include <hip/hip_fp16.h>
#include <math.h>

// Problem constants
#define V    20000
#define SCV  4000
#define LL   15
#define OUTN (16384 * 128)   // B*S*D

#define LEAF_BIT 0x40000000
#define REF_MASK 0x3FFFFFFF
#define ROOT_BIT 0x20000000   // on E.x only: node is a tree root (write hInt only)
#define SLOT_MASK 0x1FFFFFFF
#define DUMMY_SLOT 89999     // total internal nodes ~80k < 89999

// ---- workspace layout (bytes) ----
// counts int[32] @0 ; rootSlot int[V] @128 ; lists int4[240000] @80384
// leafH f32[4000*128] @3920384 ; leafC f32 @5968384 ; leafHh fp16 @8016384
// LT fp16[4000*640] @9040384 ; RT @14160384 ; WT fp16[640*256] @19280384
// biasSum f32[640] @19608064 ; hInt f32[90000*128] @19610624
// cInt f32 @65690624 ; hHalf fp16 @111770624 ; used u8[V] @134810624
#define OFF_COUNTS 0
#define OFF_ROOT   128
#define OFF_LISTS  80384
#define OFF_LEAFH  3920384
#define OFF_LEAFC  5968384
#define OFF_LEAFHH 8016384
#define OFF_LT     9040384
#define OFF_RT     14160384
#define OFF_WT     19280384
#define OFF_BIAS   19608064
#define OFF_HINT   19610624
#define OFF_CINT   65690624
#define OFF_HH     111770624
#define OFF_USED   134810624

// per-height lists: h1@0 (cap 80000), h2@80000 (40000), h3@120000 (40000),
// h4@160000, h5@180000, h6@200000, h7@220000 (20000 each)
__device__ __constant__ int d_listOff[8] = {0, 0, 80000, 120000, 160000, 180000, 200000, 220000};

#define ROUND_BLOCKS 256
#define H1_BLOCKS    1920

typedef _Float16 f16x8 __attribute__((ext_vector_type(8)));
typedef float    f32x4 __attribute__((ext_vector_type(4)));

__device__ __forceinline__ float sigm(float x) { return 1.0f / (1.0f + expf(-x)); }

// ---------------- mark kernel: which vocab entries are actually used ----------------
__global__ void mark_kernel(const int* __restrict__ input, unsigned char* __restrict__ used) {
    int i = blockIdx.x * 256 + threadIdx.x;   // 16384 threads
    used[input[i]] = 1;
}

// ---------------- leaf kernel: per sub-char-id leaf (h,c) + fp16 h ----------------
__global__ void leaf_kernel(const float* __restrict__ emb,
                            float* __restrict__ leafH, float* __restrict__ leafC,
                            __half* __restrict__ leafHh) {
    int row = blockIdx.x;       // 0..SCV-1
    int i   = threadIdx.x;      // 0..127
    const float* e = emb + row * 640;
    float ig = e[i];
    float og = e[384 + i];
    float ug = e[512 + i];
    float c = sigm(ig) * tanhf(ug);
    float h = sigm(og) * tanhf(c);
    leafH[row * 128 + i] = h;
    leafC[row * 128 + i] = c;
    leafHh[row * 128 + i] = __float2half(h);
}

// ---------------- table kernel: LT/RT fp16 tables (for h1 only) ----------------
__launch_bounds__(320)
__global__ void table_kernel(const float* __restrict__ leafH,
                             const float* __restrict__ Wl, const float* __restrict__ Wlb,
                             const float* __restrict__ Wr, const float* __restrict__ Wrb,
                             __half* __restrict__ LT, __half* __restrict__ RT) {
    __shared__ float A[16 * 128];
    int which = blockIdx.y;
    const float* W  = which ? Wr : Wl;
    const float* Wb = which ? Wrb : Wlb;
    __half* OUT     = which ? RT : LT;
    int r0 = blockIdx.x * 16;
    int t = threadIdx.x;
    for (int idx = t; idx < 16 * 128; idx += 320) A[idx] = leafH[r0 * 128 + idx];
    float acc0[16], acc1[16];
    float b0 = Wb[2 * t], b1 = Wb[2 * t + 1];
#pragma unroll
    for (int m = 0; m < 16; ++m) { acc0[m] = b0; acc1[m] = b1; }
    __syncthreads();
    const float* Bp = W + 2 * t;
#pragma unroll 1
    for (int kb = 0; kb < 128; kb += 4) {
        float4 a[16];
#pragma unroll
        for (int m = 0; m < 16; ++m) a[m] = *(const float4*)(A + (m << 7) + kb);
        float2 bb[4];
#pragma unroll
        for (int u = 0; u < 4; ++u) bb[u] = *(const float2*)(Bp + (kb + u) * 640);
#pragma unroll
        for (int u = 0; u < 4; ++u)
#pragma unroll
            for (int m = 0; m < 16; ++m) {
                float av = (&a[m].x)[u];
                acc0[m] = fmaf(av, bb[u].x, acc0[m]);
                acc1[m] = fmaf(av, bb[u].y, acc1[m]);
            }
    }
#pragma unroll
    for (int m = 0; m < 16; ++m)
        ((__half2*)OUT)[(r0 + m) * 320 + t] = __float22half2_rn(make_float2(acc0[m], acc1[m]));
}

// ---------------- WT kernel: WT[n][k] = fp16([Wl;Wr][k][n]), LDS transpose ----------------
__global__ void wt_kernel(const float* __restrict__ Wl, const float* __restrict__ Wr,
                          __half* __restrict__ WT) {
    __shared__ float T[64][65];
    int kb = blockIdx.x * 64, nb = blockIdx.y * 64;
    int tx = threadIdx.x & 63, ty = threadIdx.x >> 6;   // 256 threads
    for (int kk = ty; kk < 64; kk += 4) {
        int k = kb + kk;
        const float* Wsrc = (k < 128) ? (Wl + k * 640) : (Wr + (k - 128) * 640);
        T[kk][tx] = Wsrc[nb + tx];
    }
    __syncthreads();
    for (int nn = ty; nn < 64; nn += 4)
        WT[(nb + nn) * 256 + kb + tx] = __float2half(T[tx][nn]);
}

__global__ void bias_kernel(const float* __restrict__ Wlb, const float* __restrict__ Wrb,
                            float* __restrict__ biasSum) {
    int i = threadIdx.x;   // 640
    biasSum[i] = Wlb[i] + Wrb[i];
}

// ---------------- metadata: heights, compact slots, per-height lists ----------------
#define MT 128
__global__ void meta_kernel(const int* __restrict__ node_ids,
                            const int* __restrict__ left,
                            const int* __restrict__ right,
                            const int* __restrict__ last,
                            const unsigned char* __restrict__ used,
                            int* __restrict__ counts,
                            int* __restrict__ rootSlot,
                            int4* __restrict__ lists) {
    __shared__ int  sHei[MT][17];
    __shared__ int  sRef[MT][17];
    __shared__ int4 ebuf[MT][7];
    __shared__ int  ebin[MT][7];
    __shared__ int  locCnt[8];
    __shared__ int  basePos[8];
    __shared__ int  scanBuf[MT];
    __shared__ int  blockBase;

    int tid = threadIdx.x;
    if (tid < 8) locCnt[tid] = 0;
    __syncthreads();

    int v = blockIdx.x * MT + tid;
    int nInt = 0;
    if (v < V && used[v]) {
        int l15[LL], r15[LL], id15[LL];
#pragma unroll
        for (int j = 0; j < LL; ++j) {
            l15[j]  = left[v * LL + j];
            r15[j]  = right[v * LL + j];
            id15[j] = node_ids[v * LL + j];
        }
        int lastv = last[v];
#pragma unroll
        for (int j = 0; j < LL; ++j) {
            if (j <= lastv) {
                int l = l15[j];
                if (l < 0) {
                    sHei[tid][j] = 0;
                    sRef[tid][j] = LEAF_BIT | id15[j];
                } else {
                    int r = r15[j];
                    int hl = sHei[tid][l], hr = sHei[tid][r];
                    int hh = 1 + (hl > hr ? hl : hr);
                    sHei[tid][j] = hh;
                    int pos = atomicAdd(&locCnt[hh], 1);
                    int flag = (j == lastv) ? ROOT_BIT : 0;
                    ebuf[tid][nInt] = make_int4(nInt | flag, id15[j], sRef[tid][l], sRef[tid][r]);
                    ebin[tid][nInt] = (hh << 16) | pos;
                    sRef[tid][j] = nInt;    // local slot index (no flags)
                    ++nInt;
                }
            }
        }
    }
    // block-level inclusive scan of nInt -> compact slot bases
    scanBuf[tid] = nInt;
    __syncthreads();
    for (int d = 1; d < MT; d <<= 1) {
        int val = (tid >= d) ? scanBuf[tid - d] : 0;
        __syncthreads();
        scanBuf[tid] += val;
        __syncthreads();
    }
    if (tid == 0) blockBase = atomicAdd(&counts[31], scanBuf[MT - 1]);
    if (tid < 8) {
        int c = locCnt[tid];
        basePos[tid] = c ? atomicAdd(&counts[tid], c) : 0;
    }
    __syncthreads();
    int treeBase = blockBase + scanBuf[tid] - nInt;
    if (v < V) rootSlot[v] = treeBase + nInt - 1;   // garbage for unused v, never read
    for (int e = 0; e < nInt; ++e) {
        int4 E  = ebuf[tid][e];
        int md  = ebin[tid][e];
        int hh  = md >> 16, pos = md & 0xFFFF;
        E.x += treeBase;                                   // flag in bit29 preserved
        E.z = (E.z & LEAF_BIT) ? E.z : (E.z + treeBase);   // keep leaf tag
        E.w = (E.w & LEAF_BIT) ? E.w : (E.w + treeBase);
        lists[d_listOff[hh] + basePos[hh] + pos] = E;
    }
}

// ---------------- h1: both children leaves -> pure table gather-add ----------------
__global__ void h1_kernel(const int4* __restrict__ list, const int* __restrict__ cntPtr,
                          const float* __restrict__ emb,
                          const __half* __restrict__ LT, const __half* __restrict__ RT,
                          const float* __restrict__ leafC,
                          float* __restrict__ hInt, float* __restrict__ cInt,
                          __half* __restrict__ hH) {
    int cnt = *cntPtr;
    int j = threadIdx.x & 31;           // dim group: dims 4j..4j+3
    for (int n = blockIdx.x * 16 + (threadIdx.x >> 5); n < cnt; n += gridDim.x * 16) {
        int4 E = list[n];               // (dst|root, id, LEAF|lid, LEAF|rid)
        int li = E.z & REF_MASK, ri = E.w & REF_MASK;
        float4 ev[5]; uint2 lv[5], rv[5];
        const float* eb = emb + E.y * 640 + 4 * j;
        const uint2* lb = (const uint2*)(LT + li * 640) + j;
        const uint2* rb = (const uint2*)(RT + ri * 640) + j;
#pragma unroll
        for (int g = 0; g < 5; ++g) {
            ev[g] = *(const float4*)(eb + g * 128);
            lv[g] = lb[g * 32];
            rv[g] = rb[g * 32];
        }
        float4 cl4 = *(const float4*)(leafC + li * 128 + 4 * j);
        float4 cr4 = *(const float4*)(leafC + ri * 128 + 4 * j);
        float4 co, ho;
#pragma unroll
        for (int u = 0; u < 4; ++u) {
            float s[5];
#pragma unroll
            for (int g = 0; g < 5; ++g) {
                __half2 lh = (u < 2) ? *(__half2*)&lv[g].x : *(__half2*)&lv[g].y;
                __half2 rh = (u < 2) ? *(__half2*)&rv[g].x : *(__half2*)&rv[g].y;
                float lf = (u & 1) ? __high2float(lh) : __low2float(lh);
                float rf = (u & 1) ? __high2float(rh) : __low2float(rh);
                s[g] = (&ev[g].x)[u] + lf + rf;
            }
            float cl = (&cl4.x)[u], cr = (&cr4.x)[u];
            float c = sigm(s[0]) * tanhf(s[4]) + sigm(s[1]) * cl + sigm(s[2]) * cr;
            float h = sigm(s[3]) * tanhf(c);
            (&co.x)[u] = c; (&ho.x)[u] = h;
        }
        int slot = E.x & SLOT_MASK;
        if (E.x & ROOT_BIT) {
            // root: only the f32 h is ever read (by gather)
            *(float4*)(hInt + slot * 128 + 4 * j) = ho;
        } else {
            // non-root: only c (f32) and h (fp16) are read (by parents)
            *(float4*)(cInt + slot * 128 + 4 * j) = co;
            __half2 h0 = __float22half2_rn(make_float2(ho.x, ho.y));
            __half2 h1v = __float22half2_rn(make_float2(ho.z, ho.w));
            uint2 hp; hp.x = *(unsigned int*)&h0; hp.y = *(unsigned int*)&h1v;
            *(uint2*)(hH + slot * 128 + 4 * j) = hp;
        }
    }
}

// ---------------- MFMA round: all h>=2 nodes, unified K=256 ----------------
// Restructured for memory-level parallelism + B reuse:
//   block = 512 threads = 8 waves; per iteration 4 chunks of 16 nodes (64 rows).
//   wave w owns col-tiles {8p+w, p=0..4} = cols 128p + 16w + ln15
//     -> gate p of dim d=16w+ln15: full LSTM epilogue in registers.
//   Each B fragment (WT) feeds 4 MFMAs (one per chunk): 4x less B traffic.
//   __launch_bounds__(512,2): 256-VGPR budget so 20 acc + 5 bf + 4 af stay
//   resident and the 9 loads per K-step issue together (was: serialized at
//   VGPR_Count=84 -> ~1 load in flight -> 30us per block).
__launch_bounds__(512, 2)
__global__ void round_mfma(const int4* __restrict__ list, const int* __restrict__ cntPtr,
                           const float* __restrict__ emb, const __half* __restrict__ WT,
                           const float* __restrict__ biasSum,
                           const __half* __restrict__ leafHh, const float* __restrict__ leafC,
                           float* __restrict__ hInt, float* __restrict__ cInt,
                           __half* __restrict__ hH) {
    __shared__ __half Ah[64][264];   // +8 fp16 pad per row (same aliasing as before)
    __shared__ int4 meta[64];
    int cnt = *cntPtr;
    int nGroups = (cnt + 63) >> 6;
    int t = threadIdx.x;
    int lane = t & 63, wave = t >> 6;        // 8 waves
    int ln15 = lane & 15, quad = lane >> 4;
    for (int grp = blockIdx.x; grp < nGroups; grp += gridDim.x) {
        int base = grp * 64;
        int rows = cnt - base; if (rows > 64) rows = 64;
        if (t < 64) {
            int4 E;
            if (t < rows) E = list[base + t];
            else { E.x = DUMMY_SLOT; E.y = 0; E.z = LEAF_BIT; E.w = LEAF_BIT; }
            meta[t] = E;
        }
        __syncthreads();
        // stage A rows: [hl fp16 (k 0..127) | hr fp16 (k 128..255)], 4 loads/thread
#pragma unroll
        for (int it = 0; it < 4; ++it) {
            int idx = t + it * 512;
            int m = idx >> 5, q = idx & 31;
            int ref = (q < 16) ? meta[m].z : meta[m].w;
            const __half* hs = (ref & LEAF_BIT) ? leafHh : hH;
            uint4 v = *(const uint4*)(hs + (ref & REF_MASK) * 128 + (q & 15) * 8);
            *(uint4*)(&Ah[m][q * 8]) = v;
        }
        // C init: emb + (Wlb+Wrb); gate p lives at col offset 128p
        float bs[5];
#pragma unroll
        for (int p = 0; p < 5; ++p) bs[p] = biasSum[p * 128 + 16 * wave + ln15];
        f32x4 acc[4][5];
#pragma unroll
        for (int c = 0; c < 4; ++c)
#pragma unroll
            for (int r = 0; r < 4; ++r) {
                const float* eb = emb + meta[c * 16 + quad * 4 + r].y * 640 + 16 * wave + ln15;
#pragma unroll
                for (int p = 0; p < 5; ++p)
                    acc[c][p][r] = eb[p * 128] + bs[p];
            }
        __syncthreads();
        // K loop: 8 steps of 32; 5 B-frags + 4 A-frags feed 20 independent MFMAs
        const __half* wbase = WT + (16 * wave + ln15) * 256 + quad * 8;
#pragma unroll 2
        for (int kb = 0; kb < 8; ++kb) {
            f16x8 bf[5];
#pragma unroll
            for (int p = 0; p < 5; ++p)
                bf[p] = *(const f16x8*)((const void*)(wbase + p * 32768 + kb * 32));
            f16x8 af[4];
#pragma unroll
            for (int c = 0; c < 4; ++c)
                af[c] = *(const f16x8*)((const void*)&Ah[c * 16 + ln15][kb * 32 + quad * 8]);
#pragma unroll
            for (int p = 0; p < 5; ++p)
#pragma unroll
                for (int c = 0; c < 4; ++c)
                    acc[c][p] = __builtin_amdgcn_mfma_f32_16x16x32_f16(af[c], bf[p], acc[c][p], 0, 0, 0);
        }
        // in-register LSTM epilogue: dim d = 16*wave + ln15, gates = p
        int d = 16 * wave + ln15;
#pragma unroll
        for (int c = 0; c < 4; ++c)
#pragma unroll
            for (int r = 0; r < 4; ++r) {
                int4 E = meta[c * 16 + quad * 4 + r];
                float ig = acc[c][0][r], lfg = acc[c][1][r], rfg = acc[c][2][r];
                float og = acc[c][3][r], ug = acc[c][4][r];
                float cl = ((E.z & LEAF_BIT) ? leafC : cInt)[(E.z & REF_MASK) * 128 + d];
                float cr = ((E.w & LEAF_BIT) ? leafC : cInt)[(E.w & REF_MASK) * 128 + d];
                float cc = sigm(ig) * tanhf(ug) + sigm(lfg) * cl + sigm(rfg) * cr;
                float hh = sigm(og) * tanhf(cc);
                int slot = E.x & SLOT_MASK;
                if (E.x & ROOT_BIT) {
                    hInt[slot * 128 + d] = hh;       // root: only f32 h is read
                } else {
                    cInt[slot * 128 + d] = cc;       // non-root: c + fp16 h are read
                    hH[slot * 128 + d] = __float2half(hh);
                }
            }
        __syncthreads();   // protect meta/Ah before next group
    }
}

// ---------------- final gather: out[b,s,:] = h_root[input[b,s]] ----------------
__global__ void gather_kernel(const int* __restrict__ input,
                              const int* __restrict__ rootSlot,
                              const float* __restrict__ hInt,
                              float4* __restrict__ out) {
    int idx = blockIdx.x * 256 + threadIdx.x;   // < OUTN/4
    int token = input[idx >> 5];
    int d = idx & 31;
    out[idx] = ((const float4*)hInt)[rootSlot[token] * 32 + d];
}

extern "C" void kernel_launch(void* const* d_in, const int* in_sizes, int n_in,
                              void* d_out, int out_size, void* d_ws, size_t ws_size,
                              hipStream_t stream) {
    const int*   input    = (const int*)d_in[0];
    const int*   node_ids = (const int*)d_in[1];
    const int*   left     = (const int*)d_in[2];
    const int*   right    = (const int*)d_in[3];
    const int*   last     = (const int*)d_in[4];
    const float* emb      = (const float*)d_in[5];
    const float* Wl       = (const float*)d_in[6];
    const float* Wlb      = (const float*)d_in[7];
    const float* Wr       = (const float*)d_in[8];
    const float* Wrb      = (const float*)d_in[9];
    float* out = (float*)d_out;

    char* ws = (char*)d_ws;
    int*    counts   = (int*)(ws + OFF_COUNTS);
    int*    rootSlot = (int*)(ws + OFF_ROOT);
    int4*   lists    = (int4*)(ws + OFF_LISTS);
    float*  leafH    = (float*)(ws + OFF_LEAFH);
    float*  leafC    = (float*)(ws + OFF_LEAFC);
    __half* leafHh   = (__half*)(ws + OFF_LEAFHH);
    __half* LTp      = (__half*)(ws + OFF_LT);
    __half* RTp      = (__half*)(ws + OFF_RT);
    __half* WT       = (__half*)(ws + OFF_WT);
    float*  biasSum  = (float*)(ws + OFF_BIAS);
    float*  hInt     = (float*)(ws + OFF_HINT);
    float*  cInt     = (float*)(ws + OFF_CINT);
    __half* hH       = (__half*)(ws + OFF_HH);
    unsigned char* usedp = (unsigned char*)(ws + OFF_USED);

    (void)hipMemsetAsync(counts, 0, 128, stream);
    (void)hipMemsetAsync(usedp, 0, V, stream);

    mark_kernel<<<64, 256, 0, stream>>>(input, usedp);
    leaf_kernel<<<SCV, 128, 0, stream>>>(emb, leafH, leafC, leafHh);
    table_kernel<<<dim3(SCV / 16, 2), 320, 0, stream>>>(leafH, Wl, Wlb, Wr, Wrb, LTp, RTp);
    wt_kernel<<<dim3(4, 10), 256, 0, stream>>>(Wl, Wr, WT);
    bias_kernel<<<1, 640, 0, stream>>>(Wlb, Wrb, biasSum);
    meta_kernel<<<(V + MT - 1) / MT, MT, 0, stream>>>(node_ids, left, right, last, usedp,
                                                      counts, rootSlot, lists);

    h1_kernel<<<H1_BLOCKS, 512, 0, stream>>>(lists, counts + 1, emb, LTp, RTp, leafC,
                                             hInt, cInt, hH);

    static const int h_listOff[8] = {0, 0, 80000, 120000, 160000, 180000, 200000, 220000};
    for (int h = 2; h <= 7; ++h) {
        round_mfma<<<ROUND_BLOCKS, 512, 0, stream>>>(
            lists + h_listOff[h], counts + h,
            emb, WT, biasSum, leafHh, leafC, hInt, cInt, hH);
    }

    gather_kernel<<<OUTN / 4 / 256, 256, 0, stream>>>(input, rootSlot, hInt, (float4*)out);
}